// Round 6
// baseline (510.389 us; speedup 1.0000x reference)
//
#include <hip/hip_runtime.h>
#include <hip/hip_bf16.h>
#include <math.h>

// ---------------------------------------------------------------------------
// HyperParamNet — round 6.
// Round-5 lesson: register prefetch spilled (WRITE_SIZE 4.6->98.8 MB) on a
// 184-reg kernel. Real limiter is occupancy (2 waves/SIMD). This round:
//   * kA retiled to 8x16 tiles: acc 64->32 AGPR, hl halved, conv1/lane
//     halved -> target 3 waves/SIMD. No prefetch (inter-block overlap at
//     3 blocks/CU hides stage barriers). Math/layouts proven rounds 3-5.
//   * kC1+kC2+kC3 fused into one kernel: b1/b2 live only in LDS (kills
//     134 MB HBM round-trip + 2 launches). Conv zero-padding preserved by
//     zeroing out-of-image halo cells. Weights LDS-transposed to [tap][o]
//     for contiguous vector reads.
// ---------------------------------------------------------------------------

using s16x8 = __attribute__((ext_vector_type(8))) short;
using f32x4 = __attribute__((ext_vector_type(4))) float;

__device__ __forceinline__ float leaky(float x) {
    return x >= 0.f ? x : 0.01f * x;
}

// float -> bf16 bits, round-to-nearest-even
__device__ __forceinline__ unsigned short f2bf(float f) {
    unsigned x = __float_as_uint(f);
    return (unsigned short)((x + 0x7FFFu + ((x >> 16) & 1u)) >> 16);
}

// ---------------------------------------------------------------------------
__global__ void kInit(float* __restrict__ sums, unsigned* __restrict__ maxu) {
    int t = threadIdx.x;   // 256 == 8*32
    sums[t] = 0.f;
    maxu[t] = 0u;
}

// ---------------------------------------------------------------------------
// kA: fused conv1(grouped 3x3, VALU) + conv2(1x1, MFMA) + xc + ta reduce.
// Grid (16,32,8): 8-row x 16-col pixel tiles. Block 256 = 4 waves; wave wv
// owns rows 2wv..2wv+1 (pg=row), lane (col,lg): pixel x=col, k-slice lg.
// ---------------------------------------------------------------------------
__global__ __launch_bounds__(256, 3) void kA(
    const float* __restrict__ y, const float* __restrict__ mask,
    const float* __restrict__ fw1, const float* __restrict__ fb1,
    const float* __restrict__ fw2, const float* __restrict__ fb2,
    float* __restrict__ xc, float* __restrict__ sums, unsigned* __restrict__ maxu)
{
    __shared__ float2 shH[8 * 180];    // 8 groups x 10x18 halo (y,mask) 11520B
    __shared__ short  Wl[64 * 136];    // conv2 weights bf16, K-pad      17408B
    __shared__ float2 w1f2[112 * 9];   // conv1 weights (wy,wm)           8064B
    __shared__ float  fbl[112];        // conv1 bias                       448B
    __shared__ float  red[4 * 32 * 2]; // ta partials                     1024B

    const int b  = blockIdx.z;
    const int h0 = blockIdx.y << 3;
    const int w0 = blockIdx.x << 4;
    const int tid = threadIdx.x;
    const int wv = tid >> 6, ln = tid & 63;
    const int col = ln & 15, lg = ln >> 4;

    // ---- one-time weight staging ----
    for (int i = tid; i < 112 * 9; i += 256) {
        int ch = i / 9, q = i - ch * 9;
        w1f2[i] = make_float2(fw1[ch * 18 + q], fw1[ch * 18 + 9 + q]);
    }
    if (tid < 112) fbl[tid] = fb1[tid];
    for (int i = tid; i < 64 * 136; i += 256) {
        int o = i / 136, k = i - o * 136;
        Wl[i] = (k < 112) ? (short)f2bf(fw2[o * 112 + k]) : (short)0;
    }

    // ---- C accumulators, init with conv2 bias ----
    f32x4 acc[2][4];   // [pg][t]
    #pragma unroll
    for (int t = 0; t < 4; ++t) {
        #pragma unroll
        for (int r = 0; r < 4; ++r) {
            float bv = fb2[t * 16 + lg * 4 + r];
            acc[0][t][r] = bv;
            acc[1][t][r] = bv;
        }
    }

    // ---- K-chunk loop: 8 groups (32 temp-channels) per chunk ----
    #pragma unroll 1
    for (int s = 0; s < 4; ++s) {
        if (s) __syncthreads();            // prev compute done reading shH
        const int ng = (s == 3) ? 4 : 8;
        const int TOT = ng * 180;
        for (int i = tid; i < TOT; i += 256) {
            int g = i / 180, rem = i - g * 180;
            int r = rem / 18, c = rem - r * 18;
            int gh = h0 + r - 1, gw = w0 + c - 1;
            float2 v = make_float2(0.f, 0.f);
            if ((unsigned)gh < 256u && (unsigned)gw < 256u) {
                size_t off = (((size_t)b * 28 + s * 8 + g) << 16) + (gh << 8) + gw;
                v.x = y[off];
                v.y = mask[off];
            }
            shH[i] = v;
        }
        __syncthreads();                   // staged halo (and s=0: weights) visible

        // A-fragments (layout proven round 3)
        s16x8 A[4];
        #pragma unroll
        for (int t = 0; t < 4; ++t)
            A[t] = *(const s16x8*)&Wl[(t * 16 + col) * 136 + s * 32 + lg * 8];

        // B-fragments: conv1 computed in-lane (proven round 4)
        s16x8 Bf[2];   // [pg]
        #pragma unroll
        for (int pg = 0; pg < 2; ++pg)
            #pragma unroll
            for (int j = 0; j < 8; ++j) Bf[pg][j] = 0;

        if (s < 3 || lg < 2) {             // s=3, lg>=2 -> channels >=112
            #pragma unroll
            for (int gidx = 0; gidx < 2; ++gidx) {
                const int gl = 2 * lg + gidx;      // local group 0..7
                float2 hl[4][3];                   // 4 halo rows cover pg 0..1
                const float2* hb = &shH[gl * 180 + (2 * wv) * 18 + col];
                #pragma unroll
                for (int rr = 0; rr < 4; ++rr)
                    #pragma unroll
                    for (int cc = 0; cc < 3; ++cc)
                        hl[rr][cc] = hb[rr * 18 + cc];
                #pragma unroll
                for (int jj = 0; jj < 4; ++jj) {
                    const int chO = s * 32 + lg * 8 + gidx * 4 + jj;
                    float2 wq[9];                  // broadcast reads (~free)
                    #pragma unroll
                    for (int q = 0; q < 9; ++q) wq[q] = w1f2[chO * 9 + q];
                    const float base = fbl[chO];
                    #pragma unroll
                    for (int pg = 0; pg < 2; ++pg) {
                        float ax = base, ay = 0.f;
                        #pragma unroll
                        for (int dy = 0; dy < 3; ++dy)
                            #pragma unroll
                            for (int dx = 0; dx < 3; ++dx) {
                                float2 h = hl[pg + dy][dx];
                                float2 w = wq[dy * 3 + dx];
                                ax += w.x * h.x;
                                ay += w.y * h.y;
                            }
                        float a = fmaxf(ax + ay, 0.f);
                        Bf[pg][gidx * 4 + jj] = (short)f2bf(a);
                    }
                }
            }
        }

        #pragma unroll
        for (int pg = 0; pg < 2; ++pg)
            #pragma unroll
            for (int t = 0; t < 4; ++t)
                acc[pg][t] = __builtin_amdgcn_mfma_f32_16x16x32_bf16(
                                 A[t], Bf[pg], acc[pg][t], 0, 0, 0);
    }

    // ---- epilogue (proven rounds 3-5) ----
    float* xc0 = xc + (((size_t)b * 2) << 16);
    float* xc1 = xc0 + 65536;

    float run_s[2][4], run_m[2][4];
    #pragma unroll
    for (int t = 0; t < 2; ++t)
        #pragma unroll
        for (int r = 0; r < 4; ++r) { run_s[t][r] = 0.f; run_m[t][r] = -3.4e38f; }

    #pragma unroll
    for (int pg = 0; pg < 2; ++pg) {
        // tb (out-ch 32..63 = tiles 2,3): per-pixel max & mean -> xc
        float m8 = -3.4e38f, s8 = 0.f;
        #pragma unroll
        for (int t = 2; t < 4; ++t)
            #pragma unroll
            for (int r = 0; r < 4; ++r) {
                float v = acc[pg][t][r];
                m8 = fmaxf(m8, v); s8 += v;
            }
        m8 = fmaxf(m8, __shfl_xor(m8, 16));
        m8 = fmaxf(m8, __shfl_xor(m8, 32));
        s8 += __shfl_xor(s8, 16);
        s8 += __shfl_xor(s8, 32);
        if (ln < 16) {
            int row = h0 + 2 * wv + pg;
            xc0[(row << 8) + w0 + ln] = m8;
            xc1[(row << 8) + w0 + ln] = s8 * (1.f / 32.f);
        }
        // ta (out-ch 0..31 = tiles 0,1): running per-lane accumulate
        #pragma unroll
        for (int t = 0; t < 2; ++t)
            #pragma unroll
            for (int r = 0; r < 4; ++r) {
                float v = acc[pg][t][r];
                run_s[t][r] += v;
                run_m[t][r] = fmaxf(run_m[t][r], v);
            }
    }

    // wave reduce ta over the 16 pixel columns
    #pragma unroll
    for (int t = 0; t < 2; ++t)
        #pragma unroll
        for (int r = 0; r < 4; ++r) {
            float s = run_s[t][r], m = run_m[t][r];
            #pragma unroll
            for (int off = 1; off < 16; off <<= 1) {
                s += __shfl_xor(s, off);
                m = fmaxf(m, __shfl_xor(m, off));
            }
            if (col == 0) {
                int ch = t * 16 + lg * 4 + r;
                red[(wv * 32 + ch) * 2 + 0] = s;
                red[(wv * 32 + ch) * 2 + 1] = m;
            }
        }
    __syncthreads();
    if (tid < 32) {
        float s = red[tid*2] + red[(32+tid)*2] + red[(64+tid)*2] + red[(96+tid)*2];
        float m = fmaxf(fmaxf(red[tid*2+1], red[(32+tid)*2+1]),
                        fmaxf(red[(64+tid)*2+1], red[(96+tid)*2+1]));
        atomicAdd(&sums[b*32 + tid], s);
        unsigned ub  = __float_as_uint(m);
        unsigned key = (ub & 0x80000000u) ? ~ub : (ub | 0x80000000u);
        atomicMax(&maxu[b*32 + tid], key);
    }
}

// ---------------------------------------------------------------------------
// Kernel B: finish ta mean/max, run pgm MLP on both, alpha = sum.
// ---------------------------------------------------------------------------
__global__ __launch_bounds__(256) void kB(
    const float* __restrict__ sums, const unsigned* __restrict__ maxu,
    const float* __restrict__ aw1, const float* __restrict__ ab1,
    const float* __restrict__ aw2, const float* __restrict__ ab2,
    const float* __restrict__ aw3, const float* __restrict__ ab3,
    float* __restrict__ out)
{
    __shared__ float xa[8][32], xm[8][32], h1a[8][32], h1m[8][32];
    const int tid = threadIdx.x;
    const int b = tid >> 5, i = tid & 31;

    xa[b][i] = sums[b*32 + i] * (1.f/65536.f);
    unsigned u = maxu[b*32 + i];
    unsigned bits = (u & 0x80000000u) ? (u ^ 0x80000000u) : ~u;
    xm[b][i] = __uint_as_float(bits);
    __syncthreads();

    float sa = ab1[i], sm = ab1[i];
    #pragma unroll
    for (int j = 0; j < 32; ++j) {
        float w = aw1[i*32 + j];
        sa += w * xa[b][j]; sm += w * xm[b][j];
    }
    __syncthreads();
    h1a[b][i] = leaky(sa); h1m[b][i] = leaky(sm);
    __syncthreads();

    sa = ab2[i]; sm = ab2[i];
    #pragma unroll
    for (int j = 0; j < 32; ++j) {
        float w = aw2[i*32 + j];
        sa += w * h1a[b][j]; sm += w * h1m[b][j];
    }
    float h2a = leaky(sa), h2m = leaky(sm);

    float pa = aw3[i] * h2a, pm = aw3[i] * h2m;
    #pragma unroll
    for (int off = 16; off > 0; off >>= 1) {
        pa += __shfl_xor(pa, off);
        pm += __shfl_xor(pm, off);
    }
    if (i == 0) {
        float za = fmaxf(pa + ab3[0], 0.f) + 1e-6f;
        float zm = fmaxf(pm + ab3[0], 0.f) + 1e-6f;
        out[b] = za + zm;
    }
}

// ---------------------------------------------------------------------------
// kC: fused beta chain. Per 16x16 output tile: stage xc 22x22x2 halo,
// b1 (20x20x16) and b2 (18x18x16) entirely in LDS, then beta = sigmoid.
// Out-of-image b1/b2 halo cells are zeroed (= conv zero padding).
// ---------------------------------------------------------------------------
__global__ __launch_bounds__(256, 2) void kC(
    const float* __restrict__ xc,
    const float* __restrict__ bw1, const float* __restrict__ bb1,
    const float* __restrict__ bw2, const float* __restrict__ bb2,
    const float* __restrict__ bw3, const float* __restrict__ bb3,
    float* __restrict__ betaout)
{
    __shared__ float shX[2 * 484];     // xc halo [2][22][22]        3872B
    __shared__ float shB1[16 * 400];   // b1 [o][20][20]            25600B
    __shared__ float shB2[16 * 324];   // b2 [o][18][18]            20736B
    __shared__ float wT1[288];         // bw1^T [(ic*9+k)][o]        1152B
    __shared__ float wT2[2304];        // bw2^T [(ic*9+k)][o]        9216B

    const int b  = blockIdx.z;
    const int h0 = blockIdx.y << 4;
    const int w0 = blockIdx.x << 4;
    const int tid = threadIdx.x;

    // ---- stage transposed weights + xc halo ----
    for (int i = tid; i < 288; i += 256) {
        int o = i & 15, rest = i >> 4;           // rest = ic*9+k, ic<2
        int ic = rest / 9, k = rest - ic * 9;
        wT1[i] = bw1[(o * 2 + ic) * 9 + k];
    }
    for (int i = tid; i < 2304; i += 256) {
        int o = i & 15, rest = i >> 4;           // ic<16
        int ic = rest / 9, k = rest - ic * 9;
        wT2[i] = bw2[(o * 16 + ic) * 9 + k];
    }
    for (int i = tid; i < 968; i += 256) {
        int ch = i / 484, rem = i - ch * 484;
        int r = rem / 22, c = rem - r * 22;
        int gh = h0 + r - 3, gw = w0 + c - 3;
        float v = 0.f;
        if ((unsigned)gh < 256u && (unsigned)gw < 256u)
            v = xc[(((size_t)b * 2 + ch) << 16) + (gh << 8) + gw];
        shX[i] = v;
    }
    __syncthreads();

    // ---- phase 2: b1 = leaky(conv3x3(xc)) on 20x20 (image rows h0-2..h0+17)
    for (int p = tid; p < 400; p += 256) {
        int r1 = p / 20, c1 = p - r1 * 20;
        float a[16];
        #pragma unroll
        for (int o = 0; o < 16; ++o) a[o] = bb1[o];
        #pragma unroll
        for (int ic = 0; ic < 2; ++ic)
            #pragma unroll
            for (int dy = 0; dy < 3; ++dy)
                #pragma unroll
                for (int dx = 0; dx < 3; ++dx) {
                    float v = shX[ic * 484 + (r1 + dy) * 22 + (c1 + dx)];
                    const float* wp = &wT1[(ic * 9 + dy * 3 + dx) << 4];
                    #pragma unroll
                    for (int o = 0; o < 16; ++o) a[o] += wp[o] * v;
                }
        int gh = h0 - 2 + r1, gw = w0 - 2 + c1;
        bool valid = ((unsigned)gh < 256u) && ((unsigned)gw < 256u);
        #pragma unroll
        for (int o = 0; o < 16; ++o)
            shB1[o * 400 + p] = valid ? leaky(a[o]) : 0.f;
    }
    __syncthreads();

    // ---- phase 3: b2 = leaky(conv3x3(b1)) on 18x18 (image rows h0-1..h0+16)
    for (int p = tid; p < 324; p += 256) {
        int r2 = p / 18, c2 = p - r2 * 18;
        float a[16];
        #pragma unroll
        for (int o = 0; o < 16; ++o) a[o] = bb2[o];
        #pragma unroll 2
        for (int ic = 0; ic < 16; ++ic)
            #pragma unroll
            for (int dy = 0; dy < 3; ++dy)
                #pragma unroll
                for (int dx = 0; dx < 3; ++dx) {
                    float v = shB1[ic * 400 + (r2 + dy) * 20 + (c2 + dx)];
                    const float* wp = &wT2[(ic * 9 + dy * 3 + dx) << 4];
                    #pragma unroll
                    for (int o = 0; o < 16; ++o) a[o] += wp[o] * v;
                }
        int gh = h0 - 1 + r2, gw = w0 - 1 + c2;
        bool valid = ((unsigned)gh < 256u) && ((unsigned)gw < 256u);
        #pragma unroll
        for (int o = 0; o < 16; ++o)
            shB2[o * 324 + p] = valid ? leaky(a[o]) : 0.f;
    }
    __syncthreads();

    // ---- phase 4: beta = sigmoid(conv3x3(b2)) on the 16x16 tile ----
    {
        int r3 = tid >> 4, c3 = tid & 15;
        float a = bb3[0];
        #pragma unroll 4
        for (int ic = 0; ic < 16; ++ic)
            #pragma unroll
            for (int dy = 0; dy < 3; ++dy)
                #pragma unroll
                for (int dx = 0; dx < 3; ++dx)
                    a += bw3[ic * 9 + dy * 3 + dx]
                         * shB2[ic * 324 + (r3 + dy) * 18 + (c3 + dx)];
        betaout[((size_t)b << 16) + ((h0 + r3) << 8) + (w0 + c3)]
            = 1.f / (1.f + expf(-a));
    }
}

// ---------------------------------------------------------------------------
extern "C" void kernel_launch(void* const* d_in, const int* in_sizes, int n_in,
                              void* d_out, int out_size, void* d_ws, size_t ws_size,
                              hipStream_t stream) {
    const float* y    = (const float*)d_in[0];
    const float* mask = (const float*)d_in[1];
    const float* fw1  = (const float*)d_in[2];
    const float* fb1  = (const float*)d_in[3];
    const float* fw2  = (const float*)d_in[4];
    const float* fb2  = (const float*)d_in[5];
    const float* aw1  = (const float*)d_in[6];
    const float* ab1  = (const float*)d_in[7];
    const float* aw2  = (const float*)d_in[8];
    const float* ab2  = (const float*)d_in[9];
    const float* aw3  = (const float*)d_in[10];
    const float* ab3  = (const float*)d_in[11];
    const float* bw1  = (const float*)d_in[12];
    const float* bb1  = (const float*)d_in[13];
    const float* bw2  = (const float*)d_in[14];
    const float* bb2  = (const float*)d_in[15];
    const float* bw3  = (const float*)d_in[16];
    const float* bb3  = (const float*)d_in[17];
    float* out = (float*)d_out;

    char* ws = (char*)d_ws;
    float*    sums = (float*)ws;                 // 1 KB
    unsigned* maxu = (unsigned*)(ws + 1024);     // 1 KB
    float*    xc   = (float*)(ws + 4096);        // 4 MB

    kInit<<<1, 256, 0, stream>>>(sums, maxu);
    kA<<<dim3(16, 32, 8), 256, 0, stream>>>(y, mask, fw1, fb1, fw2, fb2,
                                            xc, sums, maxu);
    kB<<<1, 256, 0, stream>>>(sums, maxu, aw1, ab1, aw2, ab2, aw3, ab3, out);
    kC<<<dim3(16, 16, 8), 256, 0, stream>>>(xc, bw1, bb1, bw2, bb2, bw3, bb3,
                                            out + 8);
}

// Round 7
// 285.949 us; speedup vs baseline: 1.7849x; 1.7849x over previous
//
#include <hip/hip_runtime.h>
#include <hip/hip_bf16.h>
#include <math.h>

// ---------------------------------------------------------------------------
// HyperParamNet — round 7.
// Round-6 lesson: fused kC's float a[16] accumulators spilled to scratch
// (FETCH 419MB + WRITE 510MB per dispatch, VALUBusy 13%). kA's 8x16 retile
// DID work (~140us by subtraction) — kept byte-identical.
// This round (kC fix only):
//   * phases 2/3 accumulate in NAMED f32x4 vectors (a0..a3) — compile-time
//     component access only -> guaranteed registers.
//   * conv weights pre-transposed to [tap][o] in ws by kInit; kC reads them
//     as uniform f32x4 global loads (s_load_dwordx4 path, scalar cache) ->
//     no wT2 in LDS -> kC LDS 60.6KB -> 50.2KB -> 3 blocks/CU.
// ---------------------------------------------------------------------------

using s16x8 = __attribute__((ext_vector_type(8))) short;
using f32x4 = __attribute__((ext_vector_type(4))) float;

__device__ __forceinline__ float leaky(float x) {
    return x >= 0.f ? x : 0.01f * x;
}

// float -> bf16 bits, round-to-nearest-even
__device__ __forceinline__ unsigned short f2bf(float f) {
    unsigned x = __float_as_uint(f);
    return (unsigned short)((x + 0x7FFFu + ((x >> 16) & 1u)) >> 16);
}

// ---------------------------------------------------------------------------
// kInit: zero ta accumulators + transpose bw1/bw2 to [tap][o] in ws.
// ---------------------------------------------------------------------------
__global__ void kInit(float* __restrict__ sums, unsigned* __restrict__ maxu,
                      const float* __restrict__ bw1, const float* __restrict__ bw2,
                      float* __restrict__ wT1g, float* __restrict__ wT2g) {
    int t = threadIdx.x;   // 256
    sums[t] = 0.f;
    maxu[t] = 0u;
    for (int i = t; i < 288; i += 256) {      // wT1g[(ic*9+k)*16 + o]
        int o = i & 15, rest = i >> 4;        // rest = ic*9+k, ic<2
        int ic = rest / 9, k = rest - ic * 9;
        wT1g[i] = bw1[(o * 2 + ic) * 9 + k];
    }
    for (int i = t; i < 2304; i += 256) {     // wT2g[(ic*9+k)*16 + o]
        int o = i & 15, rest = i >> 4;        // ic<16
        int ic = rest / 9, k = rest - ic * 9;
        wT2g[i] = bw2[(o * 16 + ic) * 9 + k];
    }
}

// ---------------------------------------------------------------------------
// kA: fused conv1(grouped 3x3, VALU) + conv2(1x1, MFMA) + xc + ta reduce.
// UNCHANGED from round 6 (proven ~140us).
// ---------------------------------------------------------------------------
__global__ __launch_bounds__(256, 3) void kA(
    const float* __restrict__ y, const float* __restrict__ mask,
    const float* __restrict__ fw1, const float* __restrict__ fb1,
    const float* __restrict__ fw2, const float* __restrict__ fb2,
    float* __restrict__ xc, float* __restrict__ sums, unsigned* __restrict__ maxu)
{
    __shared__ float2 shH[8 * 180];    // 8 groups x 10x18 halo (y,mask) 11520B
    __shared__ short  Wl[64 * 136];    // conv2 weights bf16, K-pad      17408B
    __shared__ float2 w1f2[112 * 9];   // conv1 weights (wy,wm)           8064B
    __shared__ float  fbl[112];        // conv1 bias                       448B
    __shared__ float  red[4 * 32 * 2]; // ta partials                     1024B

    const int b  = blockIdx.z;
    const int h0 = blockIdx.y << 3;
    const int w0 = blockIdx.x << 4;
    const int tid = threadIdx.x;
    const int wv = tid >> 6, ln = tid & 63;
    const int col = ln & 15, lg = ln >> 4;

    // ---- one-time weight staging ----
    for (int i = tid; i < 112 * 9; i += 256) {
        int ch = i / 9, q = i - ch * 9;
        w1f2[i] = make_float2(fw1[ch * 18 + q], fw1[ch * 18 + 9 + q]);
    }
    if (tid < 112) fbl[tid] = fb1[tid];
    for (int i = tid; i < 64 * 136; i += 256) {
        int o = i / 136, k = i - o * 136;
        Wl[i] = (k < 112) ? (short)f2bf(fw2[o * 112 + k]) : (short)0;
    }

    // ---- C accumulators, init with conv2 bias ----
    f32x4 acc[2][4];   // [pg][t]
    #pragma unroll
    for (int t = 0; t < 4; ++t) {
        #pragma unroll
        for (int r = 0; r < 4; ++r) {
            float bv = fb2[t * 16 + lg * 4 + r];
            acc[0][t][r] = bv;
            acc[1][t][r] = bv;
        }
    }

    // ---- K-chunk loop: 8 groups (32 temp-channels) per chunk ----
    #pragma unroll 1
    for (int s = 0; s < 4; ++s) {
        if (s) __syncthreads();            // prev compute done reading shH
        const int ng = (s == 3) ? 4 : 8;
        const int TOT = ng * 180;
        for (int i = tid; i < TOT; i += 256) {
            int g = i / 180, rem = i - g * 180;
            int r = rem / 18, c = rem - r * 18;
            int gh = h0 + r - 1, gw = w0 + c - 1;
            float2 v = make_float2(0.f, 0.f);
            if ((unsigned)gh < 256u && (unsigned)gw < 256u) {
                size_t off = (((size_t)b * 28 + s * 8 + g) << 16) + (gh << 8) + gw;
                v.x = y[off];
                v.y = mask[off];
            }
            shH[i] = v;
        }
        __syncthreads();

        // A-fragments (layout proven round 3)
        s16x8 A[4];
        #pragma unroll
        for (int t = 0; t < 4; ++t)
            A[t] = *(const s16x8*)&Wl[(t * 16 + col) * 136 + s * 32 + lg * 8];

        // B-fragments: conv1 computed in-lane (proven round 4)
        s16x8 Bf[2];   // [pg]
        #pragma unroll
        for (int pg = 0; pg < 2; ++pg)
            #pragma unroll
            for (int j = 0; j < 8; ++j) Bf[pg][j] = 0;

        if (s < 3 || lg < 2) {             // s=3, lg>=2 -> channels >=112
            #pragma unroll
            for (int gidx = 0; gidx < 2; ++gidx) {
                const int gl = 2 * lg + gidx;      // local group 0..7
                float2 hl[4][3];                   // 4 halo rows cover pg 0..1
                const float2* hb = &shH[gl * 180 + (2 * wv) * 18 + col];
                #pragma unroll
                for (int rr = 0; rr < 4; ++rr)
                    #pragma unroll
                    for (int cc = 0; cc < 3; ++cc)
                        hl[rr][cc] = hb[rr * 18 + cc];
                #pragma unroll
                for (int jj = 0; jj < 4; ++jj) {
                    const int chO = s * 32 + lg * 8 + gidx * 4 + jj;
                    float2 wq[9];                  // broadcast reads (~free)
                    #pragma unroll
                    for (int q = 0; q < 9; ++q) wq[q] = w1f2[chO * 9 + q];
                    const float base = fbl[chO];
                    #pragma unroll
                    for (int pg = 0; pg < 2; ++pg) {
                        float ax = base, ay = 0.f;
                        #pragma unroll
                        for (int dy = 0; dy < 3; ++dy)
                            #pragma unroll
                            for (int dx = 0; dx < 3; ++dx) {
                                float2 h = hl[pg + dy][dx];
                                float2 w = wq[dy * 3 + dx];
                                ax += w.x * h.x;
                                ay += w.y * h.y;
                            }
                        float a = fmaxf(ax + ay, 0.f);
                        Bf[pg][gidx * 4 + jj] = (short)f2bf(a);
                    }
                }
            }
        }

        #pragma unroll
        for (int pg = 0; pg < 2; ++pg)
            #pragma unroll
            for (int t = 0; t < 4; ++t)
                acc[pg][t] = __builtin_amdgcn_mfma_f32_16x16x32_bf16(
                                 A[t], Bf[pg], acc[pg][t], 0, 0, 0);
    }

    // ---- epilogue (proven rounds 3-5) ----
    float* xc0 = xc + (((size_t)b * 2) << 16);
    float* xc1 = xc0 + 65536;

    float run_s[2][4], run_m[2][4];
    #pragma unroll
    for (int t = 0; t < 2; ++t)
        #pragma unroll
        for (int r = 0; r < 4; ++r) { run_s[t][r] = 0.f; run_m[t][r] = -3.4e38f; }

    #pragma unroll
    for (int pg = 0; pg < 2; ++pg) {
        float m8 = -3.4e38f, s8 = 0.f;
        #pragma unroll
        for (int t = 2; t < 4; ++t)
            #pragma unroll
            for (int r = 0; r < 4; ++r) {
                float v = acc[pg][t][r];
                m8 = fmaxf(m8, v); s8 += v;
            }
        m8 = fmaxf(m8, __shfl_xor(m8, 16));
        m8 = fmaxf(m8, __shfl_xor(m8, 32));
        s8 += __shfl_xor(s8, 16);
        s8 += __shfl_xor(s8, 32);
        if (ln < 16) {
            int row = h0 + 2 * wv + pg;
            xc0[(row << 8) + w0 + ln] = m8;
            xc1[(row << 8) + w0 + ln] = s8 * (1.f / 32.f);
        }
        #pragma unroll
        for (int t = 0; t < 2; ++t)
            #pragma unroll
            for (int r = 0; r < 4; ++r) {
                float v = acc[pg][t][r];
                run_s[t][r] += v;
                run_m[t][r] = fmaxf(run_m[t][r], v);
            }
    }

    #pragma unroll
    for (int t = 0; t < 2; ++t)
        #pragma unroll
        for (int r = 0; r < 4; ++r) {
            float s = run_s[t][r], m = run_m[t][r];
            #pragma unroll
            for (int off = 1; off < 16; off <<= 1) {
                s += __shfl_xor(s, off);
                m = fmaxf(m, __shfl_xor(m, off));
            }
            if (col == 0) {
                int ch = t * 16 + lg * 4 + r;
                red[(wv * 32 + ch) * 2 + 0] = s;
                red[(wv * 32 + ch) * 2 + 1] = m;
            }
        }
    __syncthreads();
    if (tid < 32) {
        float s = red[tid*2] + red[(32+tid)*2] + red[(64+tid)*2] + red[(96+tid)*2];
        float m = fmaxf(fmaxf(red[tid*2+1], red[(32+tid)*2+1]),
                        fmaxf(red[(64+tid)*2+1], red[(96+tid)*2+1]));
        atomicAdd(&sums[b*32 + tid], s);
        unsigned ub  = __float_as_uint(m);
        unsigned key = (ub & 0x80000000u) ? ~ub : (ub | 0x80000000u);
        atomicMax(&maxu[b*32 + tid], key);
    }
}

// ---------------------------------------------------------------------------
// Kernel B: finish ta mean/max, run pgm MLP on both, alpha = sum.
// ---------------------------------------------------------------------------
__global__ __launch_bounds__(256) void kB(
    const float* __restrict__ sums, const unsigned* __restrict__ maxu,
    const float* __restrict__ aw1, const float* __restrict__ ab1,
    const float* __restrict__ aw2, const float* __restrict__ ab2,
    const float* __restrict__ aw3, const float* __restrict__ ab3,
    float* __restrict__ out)
{
    __shared__ float xa[8][32], xm[8][32], h1a[8][32], h1m[8][32];
    const int tid = threadIdx.x;
    const int b = tid >> 5, i = tid & 31;

    xa[b][i] = sums[b*32 + i] * (1.f/65536.f);
    unsigned u = maxu[b*32 + i];
    unsigned bits = (u & 0x80000000u) ? (u ^ 0x80000000u) : ~u;
    xm[b][i] = __uint_as_float(bits);
    __syncthreads();

    float sa = ab1[i], sm = ab1[i];
    #pragma unroll
    for (int j = 0; j < 32; ++j) {
        float w = aw1[i*32 + j];
        sa += w * xa[b][j]; sm += w * xm[b][j];
    }
    __syncthreads();
    h1a[b][i] = leaky(sa); h1m[b][i] = leaky(sm);
    __syncthreads();

    sa = ab2[i]; sm = ab2[i];
    #pragma unroll
    for (int j = 0; j < 32; ++j) {
        float w = aw2[i*32 + j];
        sa += w * h1a[b][j]; sm += w * h1m[b][j];
    }
    float h2a = leaky(sa), h2m = leaky(sm);

    float pa = aw3[i] * h2a, pm = aw3[i] * h2m;
    #pragma unroll
    for (int off = 16; off > 0; off >>= 1) {
        pa += __shfl_xor(pa, off);
        pm += __shfl_xor(pm, off);
    }
    if (i == 0) {
        float za = fmaxf(pa + ab3[0], 0.f) + 1e-6f;
        float zm = fmaxf(pm + ab3[0], 0.f) + 1e-6f;
        out[b] = za + zm;
    }
}

// ---------------------------------------------------------------------------
// kC: fused beta chain, spill-free. Per 16x16 output tile: stage xc 22x22x2
// halo in LDS; b1 (20x20x16) and b2 (18x18x16) in LDS; beta = sigmoid.
// Accumulators are NAMED f32x4 (registers). Weights read from ws transposed
// [tap][o] as uniform f32x4 loads (scalar-cache path).
// ---------------------------------------------------------------------------
__global__ __launch_bounds__(256, 3) void kC(
    const float* __restrict__ xc,
    const float* __restrict__ wT1g, const float* __restrict__ bb1,
    const float* __restrict__ wT2g, const float* __restrict__ bb2,
    const float* __restrict__ bw3, const float* __restrict__ bb3,
    float* __restrict__ betaout)
{
    __shared__ float shX[2 * 484];     // xc halo [2][22][22]    3872B
    __shared__ float shB1[16 * 400];   // b1 [o][20][20]        25600B
    __shared__ float shB2[16 * 324];   // b2 [o][18][18]        20736B
                                       // total 50208B -> 3 blocks/CU

    const int b  = blockIdx.z;
    const int h0 = blockIdx.y << 4;
    const int w0 = blockIdx.x << 4;
    const int tid = threadIdx.x;

    // ---- stage xc halo ----
    for (int i = tid; i < 968; i += 256) {
        int ch = i / 484, rem = i - ch * 484;
        int r = rem / 22, c = rem - r * 22;
        int gh = h0 + r - 3, gw = w0 + c - 3;
        float v = 0.f;
        if ((unsigned)gh < 256u && (unsigned)gw < 256u)
            v = xc[(((size_t)b * 2 + ch) << 16) + (gh << 8) + gw];
        shX[i] = v;
    }
    __syncthreads();

    // ---- phase 2: b1 = leaky(conv3x3(xc)) on 20x20 ----
    const f32x4 bias1_0 = *(const f32x4*)&bb1[0];
    const f32x4 bias1_1 = *(const f32x4*)&bb1[4];
    const f32x4 bias1_2 = *(const f32x4*)&bb1[8];
    const f32x4 bias1_3 = *(const f32x4*)&bb1[12];
    #pragma unroll 1
    for (int p = tid; p < 400; p += 256) {
        int r1 = p / 20, c1 = p - r1 * 20;
        f32x4 a0 = bias1_0, a1 = bias1_1, a2 = bias1_2, a3 = bias1_3;
        #pragma unroll
        for (int ic = 0; ic < 2; ++ic)
            #pragma unroll
            for (int k = 0; k < 9; ++k) {
                float v = shX[ic * 484 + (r1 + k / 3) * 22 + (c1 + k % 3)];
                const f32x4* wp = (const f32x4*)&wT1g[(ic * 9 + k) << 4];
                a0 += wp[0] * v; a1 += wp[1] * v;
                a2 += wp[2] * v; a3 += wp[3] * v;
            }
        int gh = h0 - 2 + r1, gw = w0 - 2 + c1;
        if (((unsigned)gh < 256u) && ((unsigned)gw < 256u)) {
            shB1[ 0*400+p]=leaky(a0[0]); shB1[ 1*400+p]=leaky(a0[1]);
            shB1[ 2*400+p]=leaky(a0[2]); shB1[ 3*400+p]=leaky(a0[3]);
            shB1[ 4*400+p]=leaky(a1[0]); shB1[ 5*400+p]=leaky(a1[1]);
            shB1[ 6*400+p]=leaky(a1[2]); shB1[ 7*400+p]=leaky(a1[3]);
            shB1[ 8*400+p]=leaky(a2[0]); shB1[ 9*400+p]=leaky(a2[1]);
            shB1[10*400+p]=leaky(a2[2]); shB1[11*400+p]=leaky(a2[3]);
            shB1[12*400+p]=leaky(a3[0]); shB1[13*400+p]=leaky(a3[1]);
            shB1[14*400+p]=leaky(a3[2]); shB1[15*400+p]=leaky(a3[3]);
        } else {
            #pragma unroll
            for (int o = 0; o < 16; ++o) shB1[o*400+p] = 0.f;
        }
    }
    __syncthreads();

    // ---- phase 3: b2 = leaky(conv3x3(b1)) on 18x18 ----
    const f32x4 bias2_0 = *(const f32x4*)&bb2[0];
    const f32x4 bias2_1 = *(const f32x4*)&bb2[4];
    const f32x4 bias2_2 = *(const f32x4*)&bb2[8];
    const f32x4 bias2_3 = *(const f32x4*)&bb2[12];
    #pragma unroll 1
    for (int p = tid; p < 324; p += 256) {
        int r2 = p / 18, c2 = p - r2 * 18;
        f32x4 a0 = bias2_0, a1 = bias2_1, a2 = bias2_2, a3 = bias2_3;
        #pragma unroll 2
        for (int ic = 0; ic < 16; ++ic) {
            const float* base = &shB1[ic * 400 + r2 * 20 + c2];
            #pragma unroll
            for (int k = 0; k < 9; ++k) {
                float v = base[(k / 3) * 20 + (k % 3)];
                const f32x4* wp = (const f32x4*)&wT2g[(ic * 9 + k) << 4];
                a0 += wp[0] * v; a1 += wp[1] * v;
                a2 += wp[2] * v; a3 += wp[3] * v;
            }
        }
        int gh = h0 - 1 + r2, gw = w0 - 1 + c2;
        if (((unsigned)gh < 256u) && ((unsigned)gw < 256u)) {
            shB2[ 0*324+p]=leaky(a0[0]); shB2[ 1*324+p]=leaky(a0[1]);
            shB2[ 2*324+p]=leaky(a0[2]); shB2[ 3*324+p]=leaky(a0[3]);
            shB2[ 4*324+p]=leaky(a1[0]); shB2[ 5*324+p]=leaky(a1[1]);
            shB2[ 6*324+p]=leaky(a1[2]); shB2[ 7*324+p]=leaky(a1[3]);
            shB2[ 8*324+p]=leaky(a2[0]); shB2[ 9*324+p]=leaky(a2[1]);
            shB2[10*324+p]=leaky(a2[2]); shB2[11*324+p]=leaky(a2[3]);
            shB2[12*324+p]=leaky(a3[0]); shB2[13*324+p]=leaky(a3[1]);
            shB2[14*324+p]=leaky(a3[2]); shB2[15*324+p]=leaky(a3[3]);
        } else {
            #pragma unroll
            for (int o = 0; o < 16; ++o) shB2[o*324+p] = 0.f;
        }
    }
    __syncthreads();

    // ---- phase 4: beta = sigmoid(conv3x3(b2)) on the 16x16 tile ----
    {
        int r3 = tid >> 4, c3 = tid & 15;
        float a = bb3[0];
        #pragma unroll 4
        for (int ic = 0; ic < 16; ++ic)
            #pragma unroll
            for (int k = 0; k < 9; ++k)
                a += bw3[ic * 9 + k]
                     * shB2[ic * 324 + (r3 + k / 3) * 18 + (c3 + k % 3)];
        betaout[((size_t)b << 16) + ((h0 + r3) << 8) + (w0 + c3)]
            = 1.f / (1.f + expf(-a));
    }
}

// ---------------------------------------------------------------------------
extern "C" void kernel_launch(void* const* d_in, const int* in_sizes, int n_in,
                              void* d_out, int out_size, void* d_ws, size_t ws_size,
                              hipStream_t stream) {
    const float* y    = (const float*)d_in[0];
    const float* mask = (const float*)d_in[1];
    const float* fw1  = (const float*)d_in[2];
    const float* fb1  = (const float*)d_in[3];
    const float* fw2  = (const float*)d_in[4];
    const float* fb2  = (const float*)d_in[5];
    const float* aw1  = (const float*)d_in[6];
    const float* ab1  = (const float*)d_in[7];
    const float* aw2  = (const float*)d_in[8];
    const float* ab2  = (const float*)d_in[9];
    const float* aw3  = (const float*)d_in[10];
    const float* ab3  = (const float*)d_in[11];
    const float* bw1  = (const float*)d_in[12];
    const float* bb1  = (const float*)d_in[13];
    const float* bw2  = (const float*)d_in[14];
    const float* bb2  = (const float*)d_in[15];
    const float* bw3  = (const float*)d_in[16];
    const float* bb3  = (const float*)d_in[17];
    float* out = (float*)d_out;

    char* ws = (char*)d_ws;
    float*    sums = (float*)ws;                 // 1 KB
    unsigned* maxu = (unsigned*)(ws + 1024);     // 1 KB
    float*    wT1g = (float*)(ws + 2048);        // 1152 B
    float*    wT2g = (float*)(ws + 3200);        // 9216 B (ends 12416)
    float*    xc   = (float*)(ws + 16384);       // 4 MB

    kInit<<<1, 256, 0, stream>>>(sums, maxu, bw1, bw2, wT1g, wT2g);
    kA<<<dim3(16, 32, 8), 256, 0, stream>>>(y, mask, fw1, fb1, fw2, fb2,
                                            xc, sums, maxu);
    kB<<<1, 256, 0, stream>>>(sums, maxu, aw1, ab1, aw2, ab2, aw3, ab3, out);
    kC<<<dim3(16, 16, 8), 256, 0, stream>>>(xc, wT1g, bb1, wT2g, bb2, bw3, bb3,
                                            out + 8);
}